// Round 12
// baseline (126.671 us; speedup 1.0000x reference)
//
#include <hip/hip_runtime.h>
#include <hip/hip_bf16.h>

// GAT encoder, N=4096, D=128, H=8.
// k_packprep (adj->bitmask transposed [word][row]; W/W1 -> f16 transposed)
// k_wh   (Wh = nodes@W per head -> Whbt f16 [h][d][n]; f1,f2 (x log2e))
// k_m2   (per-head max M2; f16 tables e2ph[h] = [exp2(f2-M2)][exp2(a(f2-M2))])
// k_attn (fused masked-softmax + PV; R9 geometry (64-row blocks, 4 waves =
//         4 j-quarters, 4 acc row-sets/wave, 128-j dbuf DMA tiles) at
//         4 blocks/CU via __launch_bounds__(256,4); packed-f16 softmax)
// k_out  (cat@W1 + b1 with 4-way k-split, elu, +nodes residual, LayerNorm -> f32)

#define NN 4096
#define ALPHA 0.2f
#define EPSLN 1e-5f
#define LOG2E 1.4426950408889634f

typedef __attribute__((ext_vector_type(8))) _Float16 f16x8;
typedef __attribute__((ext_vector_type(4))) _Float16 f16x4;
typedef __attribute__((ext_vector_type(2))) _Float16 f16x2;
typedef __attribute__((ext_vector_type(4))) float f32x4;
typedef __attribute__((ext_vector_type(4))) int i32x4;
typedef __fp16 h16x2 __attribute__((ext_vector_type(2)));

union F16x8 { f16x8 v; f16x2 h[4]; unsigned u[4]; };
union F16x4 { f16x4 v; f16x2 h[2]; };
union PKU { f16x2 f; unsigned u; h16x2 r; };

static __device__ inline f16x2 pkrtz(float a, float b) {
  union { decltype(__builtin_amdgcn_cvt_pkrtz(0.f, 0.f)) r; f16x2 h; } u;
  u.r = __builtin_amdgcn_cvt_pkrtz(a, b);
  return u.h;
}

#if __has_builtin(__builtin_amdgcn_exp2f)
#define EXP2(x) __builtin_amdgcn_exp2f(x)
#else
#define EXP2(x) exp2f(x)
#endif

// guaranteed-packed f16 ops on u32 pairs
static __device__ __forceinline__ unsigned pk_mul(unsigned a, unsigned b) {
  unsigned d;
  asm("v_pk_mul_f16 %0, %1, %2" : "=v"(d) : "v"(a), "v"(b));
  return d;
}
static __device__ __forceinline__ unsigned pk_max(unsigned a, unsigned b) {
  unsigned d;
  asm("v_pk_max_f16 %0, %1, %2" : "=v"(d) : "v"(a), "v"(b));
  return d;
}

// v_dot2_f32_f16: c += a[0]*b[0] + a[1]*b[1]
static __device__ __forceinline__ float fdot2u(unsigned a, unsigned b, float c) {
#if __has_builtin(__builtin_amdgcn_fdot2)
  PKU ua, ub; ua.u = a; ub.u = b;
  return __builtin_amdgcn_fdot2(ua.r, ub.r, c, false);
#else
  PKU ua, ub; ua.u = a; ub.u = b;
  return c + (float)ua.f[0] * (float)ub.f[0] + (float)ua.f[1] * (float)ub.f[1];
#endif
}

// async global->LDS DMA, 16B per lane. LDS dest is wave-uniform base + lane*16.
static __device__ __forceinline__ void gload16(const void* g, void* l) {
  __builtin_amdgcn_global_load_lds(
      (const __attribute__((address_space(1))) void*)g,
      (__attribute__((address_space(3))) void*)l, 16, 0, 0);
}

static __device__ inline unsigned long long sp4(unsigned long long x) {
  x = (x | (x << 24)) & 0x000000FF000000FFULL;
  x = (x | (x << 12)) & 0x000F000F000F000FULL;
  x = (x | (x << 6))  & 0x0303030303030303ULL;
  x = (x | (x << 3))  & 0x1111111111111111ULL;
  return x;
}

// ---------------- k_packprep: blocks [0,16384): adj -> maskT; rest: W/W1 -> f16^T
__global__ void k_packprep(const int* __restrict__ adj, unsigned long long* __restrict__ maskT,
                           const float* __restrict__ W, const float* __restrict__ W1,
                           _Float16* __restrict__ Wt, _Float16* __restrict__ W1t) {
  int bid = blockIdx.x;
  if (bid < 16384) {
    int wv = threadIdx.x >> 6, l = threadIdx.x & 63;
    int gid = bid * 4 + wv;
    int row = gid >> 4, chunk = gid & 15;
    i32x4 v = *(const i32x4*)(adj + ((size_t)row << 12) + chunk * 256 + l * 4);
    unsigned long long b0 = __ballot(v.x > 0);
    unsigned long long b1 = __ballot(v.y > 0);
    unsigned long long b2 = __ballot(v.z > 0);
    unsigned long long b3 = __ballot(v.w > 0);
    if (l < 4) {
      int sh = l * 16;
      unsigned long long w = sp4((b0 >> sh) & 0xFFFF)
                           | (sp4((b1 >> sh) & 0xFFFF) << 1)
                           | (sp4((b2 >> sh) & 0xFFFF) << 2)
                           | (sp4((b3 >> sh) & 0xFFFF) << 3);
      maskT[(size_t)(chunk * 4 + l) * NN + row] = w;
    }
  } else {
    int idx = (bid - 16384) * 256 + threadIdx.x;
    if (idx < 131072) {
      int h = idx >> 14, r = idx & 16383, d = r >> 7, e = r & 127;
      Wt[h * 16384 + e * 128 + d] = (_Float16)W[idx];
    } else {
      int j = idx - 131072;
      int k = j >> 7, d = j & 127;
      W1t[d * 1024 + k] = (_Float16)W1[j];
    }
  }
}

// ---------------- k_wh: per head GEMM [4096x128]@[128x128] + f1/f2 dots
__global__ __launch_bounds__(256) void k_wh(const float* __restrict__ nodes,
    const _Float16* __restrict__ Wt, const float* __restrict__ a1,
    const float* __restrict__ a2, _Float16* __restrict__ Whbt,
    float* __restrict__ f1L, float* __restrict__ f2L) {
  int h = blockIdx.y;
  int wv = threadIdx.x >> 6, l = threadIdx.x & 63;
  int lr = l & 15, lg = l >> 4;
  int ibase = blockIdx.x * 64 + wv * 16;
  f32x4 acc[8] = {};
  const float* arow = nodes + (size_t)(ibase + lr) * 128;
  const _Float16* bbase = Wt + h * 16384;
#pragma unroll
  for (int ks = 0; ks < 4; ++ks) {
    int k0 = ks * 32 + lg * 8;
    f32x4 av0 = *(const f32x4*)(arow + k0);
    f32x4 av1 = *(const f32x4*)(arow + k0 + 4);
    F16x8 A;
    A.h[0] = pkrtz(av0[0], av0[1]);
    A.h[1] = pkrtz(av0[2], av0[3]);
    A.h[2] = pkrtz(av1[0], av1[1]);
    A.h[3] = pkrtz(av1[2], av1[3]);
#pragma unroll
    for (int nt = 0; nt < 8; ++nt) {
      f16x8 B = *(const f16x8*)(bbase + (nt * 16 + lr) * 128 + k0);
      acc[nt] = __builtin_amdgcn_mfma_f32_16x16x32_f16(A.v, B, acc[nt], 0, 0, 0);
    }
  }
#pragma unroll
  for (int nt = 0; nt < 8; ++nt) {
    F16x4 o;
    o.h[0] = pkrtz(acc[nt][0], acc[nt][1]);
    o.h[1] = pkrtz(acc[nt][2], acc[nt][3]);
    *(f16x4*)(Whbt + (size_t)(h * 128 + nt * 16 + lr) * NN + ibase + lg * 4) = o.v;
  }
  float a1r[8], a2r[8];
#pragma unroll
  for (int nt = 0; nt < 8; ++nt) {
    a1r[nt] = a1[h * 128 + nt * 16 + lr];
    a2r[nt] = a2[h * 128 + nt * 16 + lr];
  }
#pragma unroll
  for (int r = 0; r < 4; ++r) {
    float s1 = 0.f, s2 = 0.f;
#pragma unroll
    for (int nt = 0; nt < 8; ++nt) { s1 += acc[nt][r] * a1r[nt]; s2 += acc[nt][r] * a2r[nt]; }
    s1 += __shfl_xor(s1, 1, 16); s1 += __shfl_xor(s1, 2, 16);
    s1 += __shfl_xor(s1, 4, 16); s1 += __shfl_xor(s1, 8, 16);
    s2 += __shfl_xor(s2, 1, 16); s2 += __shfl_xor(s2, 2, 16);
    s2 += __shfl_xor(s2, 4, 16); s2 += __shfl_xor(s2, 8, 16);
    if (lr == 0) {
      int i = ibase + lg * 4 + r;
      f1L[h * NN + i] = s1 * LOG2E;
      f2L[h * NN + i] = s2 * LOG2E;
    }
  }
}

// ---------------- k_m2: per-head max of f2L + f16 exp tables (factors <= 1)
// e2ph[h][0][j] = exp2(f2-M2), e2ph[h][1][j] = exp2(ALPHA*(f2-M2))
__global__ __launch_bounds__(1024) void k_m2(const float* __restrict__ f2L,
    float* __restrict__ M2L, _Float16* __restrict__ e2ph) {
  __shared__ float red[16];
  int h = blockIdx.x, t = threadIdx.x;
  float a[4];
#pragma unroll
  for (int i = 0; i < 4; ++i) a[i] = f2L[h * NN + t + i * 1024];
  float v = fmaxf(fmaxf(a[0], a[1]), fmaxf(a[2], a[3]));
#pragma unroll
  for (int off = 1; off < 64; off <<= 1) v = fmaxf(v, __shfl_xor(v, off, 64));
  if ((t & 63) == 0) red[t >> 6] = v;
  __syncthreads();
  if (t < 16) {
    float m = red[t];
#pragma unroll
    for (int off = 1; off < 16; off <<= 1) m = fmaxf(m, __shfl_xor(m, off, 16));
    if (t == 0) { red[0] = m; M2L[h] = m; }
  }
  __syncthreads();
  float M2 = red[0];
#pragma unroll
  for (int i = 0; i < 4; ++i) {
    float d = a[i] - M2;
    e2ph[h * 8192 + t + i * 1024] = (_Float16)EXP2(d);
    e2ph[h * 8192 + 4096 + t + i * 1024] = (_Float16)EXP2(ALPHA * d);
  }
}

// ---------------- k_attn
// grid 512: h = bid&7 (head -> XCD, 1MB Whbt/head L2-resident), rowtile 64.
// 4 waves = 4 j-QUARTERS of each 128-j tile; every wave covers all 64 rows via
// 4 acc row-sets (acc[4][8]) -> each staged B-fragment read serves 64 rows.
// 32 tiles, ONE barrier each, dbuf B [128d][128j] 32KB x2 via global_load_lds
// (read swizzle slot^=(d&15) pre-applied to the global source), e2 f16 tables
// DMA'd (512B/tile). Masks prefetched 1 iter ahead (4 words/lane). Softmax:
// p2 = pk_max(E1*e2, Ea*e2a) & maskbits (v_pk_* asm), den via v_dot2.
// 4 blocks/CU (LDS 34.8KB, VGPR<=128 via launch_bounds(256,4)) -> TLP hides
// the per-iteration barrier/vmcnt drain that was ~30% dead time at 2 blocks.
// Epilogue: 4-phase jq-combine in LDS (spans both Bt buffers), /den+elu -> hcat.
__global__ __launch_bounds__(256, 4) void k_attn(const _Float16* __restrict__ Whbt,
    const float* __restrict__ f1L, const float* __restrict__ M2L,
    const _Float16* __restrict__ e2ph, const unsigned long long* __restrict__ maskT,
    _Float16* __restrict__ hcat) {
  __shared__ __align__(16) char Bt[2][32768];
  __shared__ __align__(16) _Float16 e2s[2][256];
  __shared__ float denL[4][64];
  int t = threadIdx.x, jq = t >> 6, l = t & 63, lr = l & 15, lg = l >> 4;
  int bid = blockIdx.x;
  int h = bid & 7;
  int rowbase = (bid >> 3) * 64;
  float M2 = M2L[h];
  unsigned E1u[4], Eau[4];
  int rg[4];
#pragma unroll
  for (int g = 0; g < 4; ++g) {
    rg[g] = rowbase + g * 16 + lr;
    float f1 = f1L[h * NN + rg[g]];
    float s = f1 + M2;
    float mL = fmaxf(s, ALPHA * s);
    float e1 = EXP2(s - mL), ea = EXP2(ALPHA * s - mL);
    PKU p1; p1.f = pkrtz(e1, e1); E1u[g] = p1.u;
    PKU p2; p2.f = pkrtz(ea, ea); Eau[g] = p2.u;
  }
  f32x4 acc[4][8] = {};
  float den[4] = {};
  const _Float16* src = Whbt + ((size_t)h << 19);
  const _Float16* ept = e2ph + h * 8192;

  // B staging: thread t pass p -> LDS linear [p*4096 + t*16] = row d = p*16+(t>>4),
  // slot t&15. Read XORs slot with d&15 -> source j-chunk jc = (t&15)^((t>>4)&15).
  int t4 = t >> 4;
  int jc = (t & 15) ^ (t4 & 15);
  size_t goff = (size_t)t4 * NN + jc * 8;
  // e2 staging (t<32): table sel (t>>4)&1, 16B chunk t&15.
  size_t gE = (size_t)(((t >> 4) & 1) * 4096) + (t & 15) * 8;
  int mshift = (jq & 1) * 32 + lg * 8;
  int wbase = jq >> 1;  // word offset within tile (0 or 1)

  // prologue: masks for iter 0, then DMA tile 0 (B + e2)
  unsigned long long mc[4];
#pragma unroll
  for (int g = 0; g < 4; ++g) mc[g] = maskT[(size_t)wbase * NN + rg[g]];
  {
    const _Float16* gp = src + goff;
    char* lb = &Bt[0][0] + t * 16;
#pragma unroll
    for (int p = 0; p < 8; ++p)
      gload16(gp + (size_t)p * 16 * NN, lb + p * 4096);
    if (t < 32) gload16(ept + gE, (char*)&e2s[0][0] + t * 16);
  }
  __syncthreads();

  for (int ct = 0; ct < 32; ++ct) {
    // prefetch next masks (regs, consumed next iter), then next tile's DMA
    unsigned long long mn[4] = {};
    if (ct + 1 < 32) {
#pragma unroll
      for (int g = 0; g < 4; ++g)
        mn[g] = maskT[(size_t)((ct + 1) * 2 + wbase) * NN + rg[g]];
      const _Float16* gp = src + goff + (ct + 1) * 128;
      char* lb = &Bt[(ct + 1) & 1][0] + t * 16;
#pragma unroll
      for (int p = 0; p < 8; ++p)
        gload16(gp + (size_t)p * 16 * NN, lb + p * 4096);
      if (t < 32) gload16(ept + gE + (ct + 1) * 128, (char*)&e2s[(ct + 1) & 1][0] + t * 16);
    }
    const char* btr = &Bt[ct & 1][0];
    const char* e2p = (const char*)&e2s[ct & 1][0];
    // e2/e2a pairs for this wave's 8 j (4 u32 pairs each)
    i32x4 e2w = *(const i32x4*)(e2p + jq * 64 + lg * 16);
    i32x4 e2aw = *(const i32x4*)(e2p + 256 + jq * 64 + lg * 16);
    // build 4 A-fragments (one per row-set)
    F16x8 afr[4];
#pragma unroll
    for (int g = 0; g < 4; ++g) {
      unsigned bits = (unsigned)(mc[g] >> mshift) & 0xFFu;
      float dg = den[g];
#pragma unroll
      for (int pi = 0; pi < 4; ++pi) {
        unsigned mx = pk_max(pk_mul(E1u[g], (unsigned)e2w[pi]),
                             pk_mul(Eau[g], (unsigned)e2aw[pi]));
        unsigned b = (bits >> (2 * pi)) & 3u;
        mx &= ((b & 1u) ? 0x0000FFFFu : 0u) | ((b & 2u) ? 0xFFFF0000u : 0u);
        afr[g].u[pi] = mx;
        dg = fdot2u(mx, 0x3C003C00u, dg);  // += pair sum (ones)
      }
      den[g] = dg;
    }
    __builtin_amdgcn_s_setprio(1);
#pragma unroll
    for (int nt = 0; nt < 8; ++nt) {
      int d = nt * 16 + lr;
      int byteoff = d * 256 + (((jq * 4 + lg) ^ lr) << 4);
      f16x8 B = *(const f16x8*)(btr + byteoff);
#pragma unroll
      for (int g = 0; g < 4; ++g)
        acc[g][nt] = __builtin_amdgcn_mfma_f32_16x16x32_f16(afr[g].v, B, acc[g][nt], 0, 0, 0);
    }
    __builtin_amdgcn_s_setprio(0);
    __syncthreads();  // drains next-tile DMA; orders buffer reuse
#pragma unroll
    for (int g = 0; g < 4; ++g) mc[g] = mn[g];
  }
  // reduce den over the 4 j-subgroups (lg); store per-quarter partials
#pragma unroll
  for (int g = 0; g < 4; ++g) {
    den[g] += __shfl_xor(den[g], 16, 64);
    den[g] += __shfl_xor(den[g], 32, 64);
  }
  if (l < 16) {
#pragma unroll
    for (int g = 0; g < 4; ++g) denL[jq][g * 16 + lr] = den[g];
  }

  // 4-phase j-quarter combine into [64][132] f32 (33.8KB, spans Bt[0..1])
  float* cmb = (float*)Bt;
#pragma unroll
  for (int ph = 0; ph < 4; ++ph) {
    if (jq == ph) {
      if (ph == 0) {
#pragma unroll
        for (int g = 0; g < 4; ++g)
#pragma unroll
          for (int nt = 0; nt < 8; ++nt)
#pragma unroll
            for (int r = 0; r < 4; ++r)
              cmb[(g * 16 + lg * 4 + r) * 132 + nt * 16 + lr] = acc[g][nt][r];
      } else {
#pragma unroll
        for (int g = 0; g < 4; ++g)
#pragma unroll
          for (int nt = 0; nt < 8; ++nt)
#pragma unroll
            for (int r = 0; r < 4; ++r)
              cmb[(g * 16 + lg * 4 + r) * 132 + nt * 16 + lr] += acc[g][nt][r];
      }
    }
    __syncthreads();
  }
  // epilogue: /den + elu + coalesced f16 store. thread t: row t>>2, 32-col seg t&3
  {
    int row = t >> 2, seg = t & 3;
    const float* rgp = cmb + row * 132 + seg * 32;
    float dsum = denL[0][row] + denL[1][row] + denL[2][row] + denL[3][row];
    float rc = __builtin_amdgcn_rcpf(dsum);
    _Float16* outp = hcat + (size_t)(rowbase + row) * 1024 + h * 128 + seg * 32;
#pragma unroll
    for (int q8 = 0; q8 < 4; ++q8) {
      f32x4 va = *(const f32x4*)(rgp + q8 * 8);
      f32x4 vb = *(const f32x4*)(rgp + q8 * 8 + 4);
      float x[8];
#pragma unroll
      for (int c = 0; c < 4; ++c) { x[c] = va[c] * rc; x[4 + c] = vb[c] * rc; }
#pragma unroll
      for (int c = 0; c < 8; ++c) x[c] = x[c] > 0.f ? x[c] : EXP2(x[c] * LOG2E) - 1.f;
      F16x8 o;
      o.h[0] = pkrtz(x[0], x[1]); o.h[1] = pkrtz(x[2], x[3]);
      o.h[2] = pkrtz(x[4], x[5]); o.h[3] = pkrtz(x[6], x[7]);
      *(f16x8*)(outp + q8 * 8) = o.v;
    }
  }
}

// ---------------- k_out: x = elu(cat@W1 + b1); out = LN(nodes + x)
// 256 blocks x 256 thr: 16 rows/block, 4 waves k-split (256 k each), LDS combine.
__global__ __launch_bounds__(256) void k_out(const _Float16* __restrict__ hcat,
    const _Float16* __restrict__ W1t, const float* __restrict__ b1,
    const float* __restrict__ nodes, const float* __restrict__ gamma,
    const float* __restrict__ beta, float* __restrict__ out) {
  __shared__ __align__(16) float part[4][16][132];
  int t = threadIdx.x, w = t >> 6, l = t & 63, lr = l & 15, lg = l >> 4;
  int ibase = blockIdx.x * 16;
  f32x4 acc[8] = {};
  const _Float16* arow = hcat + (size_t)(ibase + lr) * 1024 + w * 256;
  const _Float16* bb = W1t + w * 256;
#pragma unroll
  for (int ks = 0; ks < 8; ++ks) {
    int k0 = ks * 32 + lg * 8;
    f16x8 A = *(const f16x8*)(arow + k0);
#pragma unroll
    for (int nt = 0; nt < 8; ++nt) {
      f16x8 B = *(const f16x8*)(bb + (nt * 16 + lr) * 1024 + k0);
      acc[nt] = __builtin_amdgcn_mfma_f32_16x16x32_f16(A, B, acc[nt], 0, 0, 0);
    }
  }
#pragma unroll
  for (int nt = 0; nt < 8; ++nt)
#pragma unroll
    for (int r = 0; r < 4; ++r)
      part[w][lg * 4 + r][nt * 16 + lr] = acc[nt][r];
  __syncthreads();
  int row = t >> 4, c16 = t & 15;
  int d0 = c16 * 8;
  size_t gi = (size_t)(ibase + row) * 128;
  f32x4 pa = {}, pb = {};
#pragma unroll
  for (int qq = 0; qq < 4; ++qq) {
    pa += *(const f32x4*)&part[qq][row][d0];
    pb += *(const f32x4*)&part[qq][row][d0 + 4];
  }
  f32x4 ba = *(const f32x4*)(b1 + d0), bbv = *(const f32x4*)(b1 + d0 + 4);
  f32x4 na = *(const f32x4*)(nodes + gi + d0), nb = *(const f32x4*)(nodes + gi + d0 + 4);
  float y[8];
  float sum = 0.f, sq = 0.f;
#pragma unroll
  for (int c = 0; c < 4; ++c) {
    float x = pa[c] + ba[c];
    x = x > 0.f ? x : EXP2(x * LOG2E) - 1.f;
    y[c] = x + na[c];
    float x2 = pb[c] + bbv[c];
    x2 = x2 > 0.f ? x2 : EXP2(x2 * LOG2E) - 1.f;
    y[4 + c] = x2 + nb[c];
  }
#pragma unroll
  for (int c = 0; c < 8; ++c) { sum += y[c]; sq += y[c] * y[c]; }
#pragma unroll
  for (int off = 1; off < 16; off <<= 1) {
    sum += __shfl_xor(sum, off, 16);
    sq += __shfl_xor(sq, off, 16);
  }
  float mu = sum * (1.f / 128.f);
  float var = sq * (1.f / 128.f) - mu * mu;
  float rs = __builtin_amdgcn_rsqf(var + EPSLN);
  f32x4 ga = *(const f32x4*)(gamma + d0), gb = *(const f32x4*)(gamma + d0 + 4);
  f32x4 bea = *(const f32x4*)(beta + d0), beb = *(const f32x4*)(beta + d0 + 4);
  f32x4 o0, o1;
#pragma unroll
  for (int c = 0; c < 4; ++c) {
    o0[c] = (y[c] - mu) * rs * ga[c] + bea[c];
    o1[c] = (y[4 + c] - mu) * rs * gb[c] + beb[c];
  }
  *(f32x4*)(out + gi + d0) = o0;
  *(f32x4*)(out + gi + d0 + 4) = o1;
}

extern "C" void kernel_launch(void* const* d_in, const int* in_sizes, int n_in,
                              void* d_out, int out_size, void* d_ws, size_t ws_size,
                              hipStream_t stream) {
  const float* nodes = (const float*)d_in[0];
  const int* adj = (const int*)d_in[1];
  const float* W = (const float*)d_in[2];
  const float* a1 = (const float*)d_in[3];
  const float* a2 = (const float*)d_in[4];
  const float* W1 = (const float*)d_in[5];
  const float* b1 = (const float*)d_in[6];
  const float* gamma = (const float*)d_in[7];
  const float* beta = (const float*)d_in[8];
  float* out = (float*)d_out;
  char* ws = (char*)d_ws;

  const size_t OFF_MASK = 0;                       // 2 MB
  const size_t OFF_WHBT = 2097152;                 // 8.4 MB
  const size_t OFF_F1 = OFF_WHBT + 8388608;        // 128 KB
  const size_t OFF_F2 = OFF_F1 + 131072;           // 128 KB
  const size_t OFF_M2 = OFF_F2 + 131072;           // 256 B
  const size_t OFF_E2T = OFF_M2 + 256;             // 128 KB (f16 tables)
  const size_t OFF_WT = OFF_E2T + 131072;          // 256 KB
  const size_t OFF_W1T = OFF_WT + 262144;          // 256 KB
  const size_t OFF_HCAT = OFF_W1T + 262144;        // 8.4 MB

  unsigned long long* maskT = (unsigned long long*)(ws + OFF_MASK);
  _Float16* Whbt = (_Float16*)(ws + OFF_WHBT);
  float* f1L = (float*)(ws + OFF_F1);
  float* f2L = (float*)(ws + OFF_F2);
  float* M2L = (float*)(ws + OFF_M2);
  _Float16* e2ph = (_Float16*)(ws + OFF_E2T);
  _Float16* Wt = (_Float16*)(ws + OFF_WT);
  _Float16* W1t = (_Float16*)(ws + OFF_W1T);
  _Float16* hcat = (_Float16*)(ws + OFF_HCAT);

  k_packprep<<<17408, 256, 0, stream>>>(adj, maskT, W, W1, Wt, W1t);
  k_wh<<<dim3(64, 8), 256, 0, stream>>>(nodes, Wt, a1, a2, Whbt, f1L, f2L);
  k_m2<<<8, 1024, 0, stream>>>(f2L, M2L, e2ph);
  k_attn<<<512, 256, 0, stream>>>(Whbt, f1L, M2L, e2ph, maskT, hcat);
  k_out<<<256, 256, 0, stream>>>(hcat, W1t, b1, nodes, gamma, beta, out);
}

// Round 13
// 92.718 us; speedup vs baseline: 1.3662x; 1.3662x over previous
//
#include <hip/hip_runtime.h>
#include <hip/hip_bf16.h>

// GAT encoder, N=4096, D=128, H=8.  (Best-known configuration: R9 revert.)
// k_packprep (adj->bitmask transposed [word][row]; W/W1 -> f16 transposed)
// k_wh   (Wh = nodes@W per head -> Whbt f16 [h][d][n]; f1,f2 (x log2e))
// k_m2   (per-head max M2; f16 tables e2ph[h] = [exp2(f2-M2)][exp2(a(f2-M2))])
// k_attn (fused masked-softmax + PV; 64-row blocks, 4 waves = 4 j-quarters,
//         4 acc row-sets/wave (reads amortized over 64 rows), 128-j dbuf DMA
//         tiles, packed-f16 softmax via v_pk_* asm; epilogue -> hcat f16)
// k_out  (cat@W1 + b1 with 4-way k-split, elu, +nodes residual, LayerNorm -> f32)

#define NN 4096
#define ALPHA 0.2f
#define EPSLN 1e-5f
#define LOG2E 1.4426950408889634f

typedef __attribute__((ext_vector_type(8))) _Float16 f16x8;
typedef __attribute__((ext_vector_type(4))) _Float16 f16x4;
typedef __attribute__((ext_vector_type(2))) _Float16 f16x2;
typedef __attribute__((ext_vector_type(4))) float f32x4;
typedef __attribute__((ext_vector_type(4))) int i32x4;
typedef __fp16 h16x2 __attribute__((ext_vector_type(2)));

union F16x8 { f16x8 v; f16x2 h[4]; unsigned u[4]; };
union F16x4 { f16x4 v; f16x2 h[2]; };
union PKU { f16x2 f; unsigned u; h16x2 r; };

static __device__ inline f16x2 pkrtz(float a, float b) {
  union { decltype(__builtin_amdgcn_cvt_pkrtz(0.f, 0.f)) r; f16x2 h; } u;
  u.r = __builtin_amdgcn_cvt_pkrtz(a, b);
  return u.h;
}

#if __has_builtin(__builtin_amdgcn_exp2f)
#define EXP2(x) __builtin_amdgcn_exp2f(x)
#else
#define EXP2(x) exp2f(x)
#endif

// guaranteed-packed f16 ops on u32 pairs
static __device__ __forceinline__ unsigned pk_mul(unsigned a, unsigned b) {
  unsigned d;
  asm("v_pk_mul_f16 %0, %1, %2" : "=v"(d) : "v"(a), "v"(b));
  return d;
}
static __device__ __forceinline__ unsigned pk_max(unsigned a, unsigned b) {
  unsigned d;
  asm("v_pk_max_f16 %0, %1, %2" : "=v"(d) : "v"(a), "v"(b));
  return d;
}

// v_dot2_f32_f16: c += a[0]*b[0] + a[1]*b[1]
static __device__ __forceinline__ float fdot2u(unsigned a, unsigned b, float c) {
#if __has_builtin(__builtin_amdgcn_fdot2)
  PKU ua, ub; ua.u = a; ub.u = b;
  return __builtin_amdgcn_fdot2(ua.r, ub.r, c, false);
#else
  PKU ua, ub; ua.u = a; ub.u = b;
  return c + (float)ua.f[0] * (float)ub.f[0] + (float)ua.f[1] * (float)ub.f[1];
#endif
}

// async global->LDS DMA, 16B per lane. LDS dest is wave-uniform base + lane*16.
static __device__ __forceinline__ void gload16(const void* g, void* l) {
  __builtin_amdgcn_global_load_lds(
      (const __attribute__((address_space(1))) void*)g,
      (__attribute__((address_space(3))) void*)l, 16, 0, 0);
}

static __device__ inline unsigned long long sp4(unsigned long long x) {
  x = (x | (x << 24)) & 0x000000FF000000FFULL;
  x = (x | (x << 12)) & 0x000F000F000F000FULL;
  x = (x | (x << 6))  & 0x0303030303030303ULL;
  x = (x | (x << 3))  & 0x1111111111111111ULL;
  return x;
}

// ---------------- k_packprep: blocks [0,16384): adj -> maskT; rest: W/W1 -> f16^T
__global__ void k_packprep(const int* __restrict__ adj, unsigned long long* __restrict__ maskT,
                           const float* __restrict__ W, const float* __restrict__ W1,
                           _Float16* __restrict__ Wt, _Float16* __restrict__ W1t) {
  int bid = blockIdx.x;
  if (bid < 16384) {
    int wv = threadIdx.x >> 6, l = threadIdx.x & 63;
    int gid = bid * 4 + wv;
    int row = gid >> 4, chunk = gid & 15;
    i32x4 v = *(const i32x4*)(adj + ((size_t)row << 12) + chunk * 256 + l * 4);
    unsigned long long b0 = __ballot(v.x > 0);
    unsigned long long b1 = __ballot(v.y > 0);
    unsigned long long b2 = __ballot(v.z > 0);
    unsigned long long b3 = __ballot(v.w > 0);
    if (l < 4) {
      int sh = l * 16;
      unsigned long long w = sp4((b0 >> sh) & 0xFFFF)
                           | (sp4((b1 >> sh) & 0xFFFF) << 1)
                           | (sp4((b2 >> sh) & 0xFFFF) << 2)
                           | (sp4((b3 >> sh) & 0xFFFF) << 3);
      maskT[(size_t)(chunk * 4 + l) * NN + row] = w;
    }
  } else {
    int idx = (bid - 16384) * 256 + threadIdx.x;
    if (idx < 131072) {
      int h = idx >> 14, r = idx & 16383, d = r >> 7, e = r & 127;
      Wt[h * 16384 + e * 128 + d] = (_Float16)W[idx];
    } else {
      int j = idx - 131072;
      int k = j >> 7, d = j & 127;
      W1t[d * 1024 + k] = (_Float16)W1[j];
    }
  }
}

// ---------------- k_wh: per head GEMM [4096x128]@[128x128] + f1/f2 dots
__global__ __launch_bounds__(256) void k_wh(const float* __restrict__ nodes,
    const _Float16* __restrict__ Wt, const float* __restrict__ a1,
    const float* __restrict__ a2, _Float16* __restrict__ Whbt,
    float* __restrict__ f1L, float* __restrict__ f2L) {
  int h = blockIdx.y;
  int wv = threadIdx.x >> 6, l = threadIdx.x & 63;
  int lr = l & 15, lg = l >> 4;
  int ibase = blockIdx.x * 64 + wv * 16;
  f32x4 acc[8] = {};
  const float* arow = nodes + (size_t)(ibase + lr) * 128;
  const _Float16* bbase = Wt + h * 16384;
#pragma unroll
  for (int ks = 0; ks < 4; ++ks) {
    int k0 = ks * 32 + lg * 8;
    f32x4 av0 = *(const f32x4*)(arow + k0);
    f32x4 av1 = *(const f32x4*)(arow + k0 + 4);
    F16x8 A;
    A.h[0] = pkrtz(av0[0], av0[1]);
    A.h[1] = pkrtz(av0[2], av0[3]);
    A.h[2] = pkrtz(av1[0], av1[1]);
    A.h[3] = pkrtz(av1[2], av1[3]);
#pragma unroll
    for (int nt = 0; nt < 8; ++nt) {
      f16x8 B = *(const f16x8*)(bbase + (nt * 16 + lr) * 128 + k0);
      acc[nt] = __builtin_amdgcn_mfma_f32_16x16x32_f16(A.v, B, acc[nt], 0, 0, 0);
    }
  }
#pragma unroll
  for (int nt = 0; nt < 8; ++nt) {
    F16x4 o;
    o.h[0] = pkrtz(acc[nt][0], acc[nt][1]);
    o.h[1] = pkrtz(acc[nt][2], acc[nt][3]);
    *(f16x4*)(Whbt + (size_t)(h * 128 + nt * 16 + lr) * NN + ibase + lg * 4) = o.v;
  }
  float a1r[8], a2r[8];
#pragma unroll
  for (int nt = 0; nt < 8; ++nt) {
    a1r[nt] = a1[h * 128 + nt * 16 + lr];
    a2r[nt] = a2[h * 128 + nt * 16 + lr];
  }
#pragma unroll
  for (int r = 0; r < 4; ++r) {
    float s1 = 0.f, s2 = 0.f;
#pragma unroll
    for (int nt = 0; nt < 8; ++nt) { s1 += acc[nt][r] * a1r[nt]; s2 += acc[nt][r] * a2r[nt]; }
    s1 += __shfl_xor(s1, 1, 16); s1 += __shfl_xor(s1, 2, 16);
    s1 += __shfl_xor(s1, 4, 16); s1 += __shfl_xor(s1, 8, 16);
    s2 += __shfl_xor(s2, 1, 16); s2 += __shfl_xor(s2, 2, 16);
    s2 += __shfl_xor(s2, 4, 16); s2 += __shfl_xor(s2, 8, 16);
    if (lr == 0) {
      int i = ibase + lg * 4 + r;
      f1L[h * NN + i] = s1 * LOG2E;
      f2L[h * NN + i] = s2 * LOG2E;
    }
  }
}

// ---------------- k_m2: per-head max of f2L + f16 exp tables (factors <= 1)
// e2ph[h][0][j] = exp2(f2-M2), e2ph[h][1][j] = exp2(ALPHA*(f2-M2))
__global__ __launch_bounds__(1024) void k_m2(const float* __restrict__ f2L,
    float* __restrict__ M2L, _Float16* __restrict__ e2ph) {
  __shared__ float red[16];
  int h = blockIdx.x, t = threadIdx.x;
  float a[4];
#pragma unroll
  for (int i = 0; i < 4; ++i) a[i] = f2L[h * NN + t + i * 1024];
  float v = fmaxf(fmaxf(a[0], a[1]), fmaxf(a[2], a[3]));
#pragma unroll
  for (int off = 1; off < 64; off <<= 1) v = fmaxf(v, __shfl_xor(v, off, 64));
  if ((t & 63) == 0) red[t >> 6] = v;
  __syncthreads();
  if (t < 16) {
    float m = red[t];
#pragma unroll
    for (int off = 1; off < 16; off <<= 1) m = fmaxf(m, __shfl_xor(m, off, 16));
    if (t == 0) { red[0] = m; M2L[h] = m; }
  }
  __syncthreads();
  float M2 = red[0];
#pragma unroll
  for (int i = 0; i < 4; ++i) {
    float d = a[i] - M2;
    e2ph[h * 8192 + t + i * 1024] = (_Float16)EXP2(d);
    e2ph[h * 8192 + 4096 + t + i * 1024] = (_Float16)EXP2(ALPHA * d);
  }
}

// ---------------- k_attn
// grid 512: h = bid&7 (head -> XCD, 1MB Whbt/head L2-resident), rowtile 64.
// 4 waves = 4 j-QUARTERS of each 128-j tile; every wave covers all 64 rows via
// 4 acc row-sets (acc[4][8]) -> each staged B-fragment read serves 64 rows.
// 32 tiles, ONE barrier each, dbuf B [128d][128j] 32KB x2 via global_load_lds
// (read swizzle slot^=(d&15) pre-applied to the global source), e2 f16 tables
// DMA'd (512B/tile). Masks prefetched 1 iter ahead (4 words/lane). Softmax:
// p2 = pk_max(E1*e2, Ea*e2a) & maskbits (v_pk_* asm), den via v_dot2.
// Epilogue: 4-phase jq-combine in LDS (spans both Bt buffers), /den+elu -> hcat.
// NOTE: LDS = 67.6KB -> 2 blocks/CU; acc[4][8] (128 f32) + ~70 arch VGPR caps
// at 2 waves/SIMD, so launch_bounds(256,2) is the FEASIBLE maximum (R12's
// (256,4) was infeasible and regressed regalloc: VGPR 140, occ 10.8%).
__global__ __launch_bounds__(256, 2) void k_attn(const _Float16* __restrict__ Whbt,
    const float* __restrict__ f1L, const float* __restrict__ M2L,
    const _Float16* __restrict__ e2ph, const unsigned long long* __restrict__ maskT,
    _Float16* __restrict__ hcat) {
  __shared__ __align__(16) char Bt[2][32768];
  __shared__ __align__(16) _Float16 e2s[2][256];
  __shared__ float denL[4][64];
  int t = threadIdx.x, jq = t >> 6, l = t & 63, lr = l & 15, lg = l >> 4;
  int bid = blockIdx.x;
  int h = bid & 7;
  int rowbase = (bid >> 3) * 64;
  float M2 = M2L[h];
  unsigned E1u[4], Eau[4];
  int rg[4];
#pragma unroll
  for (int g = 0; g < 4; ++g) {
    rg[g] = rowbase + g * 16 + lr;
    float f1 = f1L[h * NN + rg[g]];
    float s = f1 + M2;
    float mL = fmaxf(s, ALPHA * s);
    float e1 = EXP2(s - mL), ea = EXP2(ALPHA * s - mL);
    PKU p1; p1.f = pkrtz(e1, e1); E1u[g] = p1.u;
    PKU p2; p2.f = pkrtz(ea, ea); Eau[g] = p2.u;
  }
  f32x4 acc[4][8] = {};
  float den[4] = {};
  const _Float16* src = Whbt + ((size_t)h << 19);
  const _Float16* ept = e2ph + h * 8192;

  // B staging: thread t pass p -> LDS linear [p*4096 + t*16] = row d = p*16+(t>>4),
  // slot t&15. Read XORs slot with d&15 -> source j-chunk jc = (t&15)^((t>>4)&15).
  int t4 = t >> 4;
  int jc = (t & 15) ^ (t4 & 15);
  size_t goff = (size_t)t4 * NN + jc * 8;
  // e2 staging (t<32): table sel (t>>4)&1, 16B chunk t&15.
  size_t gE = (size_t)(((t >> 4) & 1) * 4096) + (t & 15) * 8;
  int mshift = (jq & 1) * 32 + lg * 8;
  int wbase = jq >> 1;  // word offset within tile (0 or 1)

  // prologue: masks for iter 0, then DMA tile 0 (B + e2)
  unsigned long long mc[4];
#pragma unroll
  for (int g = 0; g < 4; ++g) mc[g] = maskT[(size_t)wbase * NN + rg[g]];
  {
    const _Float16* gp = src + goff;
    char* lb = &Bt[0][0] + t * 16;
#pragma unroll
    for (int p = 0; p < 8; ++p)
      gload16(gp + (size_t)p * 16 * NN, lb + p * 4096);
    if (t < 32) gload16(ept + gE, (char*)&e2s[0][0] + t * 16);
  }
  __syncthreads();

  for (int ct = 0; ct < 32; ++ct) {
    // prefetch next masks (regs, consumed next iter), then next tile's DMA
    unsigned long long mn[4] = {};
    if (ct + 1 < 32) {
#pragma unroll
      for (int g = 0; g < 4; ++g)
        mn[g] = maskT[(size_t)((ct + 1) * 2 + wbase) * NN + rg[g]];
      const _Float16* gp = src + goff + (ct + 1) * 128;
      char* lb = &Bt[(ct + 1) & 1][0] + t * 16;
#pragma unroll
      for (int p = 0; p < 8; ++p)
        gload16(gp + (size_t)p * 16 * NN, lb + p * 4096);
      if (t < 32) gload16(ept + gE + (ct + 1) * 128, (char*)&e2s[(ct + 1) & 1][0] + t * 16);
    }
    const char* btr = &Bt[ct & 1][0];
    const char* e2p = (const char*)&e2s[ct & 1][0];
    // e2/e2a pairs for this wave's 8 j (4 u32 pairs each)
    i32x4 e2w = *(const i32x4*)(e2p + jq * 64 + lg * 16);
    i32x4 e2aw = *(const i32x4*)(e2p + 256 + jq * 64 + lg * 16);
    // build 4 A-fragments (one per row-set)
    F16x8 afr[4];
#pragma unroll
    for (int g = 0; g < 4; ++g) {
      unsigned bits = (unsigned)(mc[g] >> mshift) & 0xFFu;
      float dg = den[g];
#pragma unroll
      for (int pi = 0; pi < 4; ++pi) {
        unsigned mx = pk_max(pk_mul(E1u[g], (unsigned)e2w[pi]),
                             pk_mul(Eau[g], (unsigned)e2aw[pi]));
        unsigned b = (bits >> (2 * pi)) & 3u;
        mx &= ((b & 1u) ? 0x0000FFFFu : 0u) | ((b & 2u) ? 0xFFFF0000u : 0u);
        afr[g].u[pi] = mx;
        dg = fdot2u(mx, 0x3C003C00u, dg);  // += pair sum (ones)
      }
      den[g] = dg;
    }
    __builtin_amdgcn_s_setprio(1);
#pragma unroll
    for (int nt = 0; nt < 8; ++nt) {
      int d = nt * 16 + lr;
      int byteoff = d * 256 + (((jq * 4 + lg) ^ lr) << 4);
      f16x8 B = *(const f16x8*)(btr + byteoff);
#pragma unroll
      for (int g = 0; g < 4; ++g)
        acc[g][nt] = __builtin_amdgcn_mfma_f32_16x16x32_f16(afr[g].v, B, acc[g][nt], 0, 0, 0);
    }
    __builtin_amdgcn_s_setprio(0);
    __syncthreads();  // drains next-tile DMA; orders buffer reuse
#pragma unroll
    for (int g = 0; g < 4; ++g) mc[g] = mn[g];
  }
  // reduce den over the 4 j-subgroups (lg); store per-quarter partials
#pragma unroll
  for (int g = 0; g < 4; ++g) {
    den[g] += __shfl_xor(den[g], 16, 64);
    den[g] += __shfl_xor(den[g], 32, 64);
  }
  if (l < 16) {
#pragma unroll
    for (int g = 0; g < 4; ++g) denL[jq][g * 16 + lr] = den[g];
  }

  // 4-phase j-quarter combine into [64][132] f32 (33.8KB, spans Bt[0..1])
  float* cmb = (float*)Bt;
#pragma unroll
  for (int ph = 0; ph < 4; ++ph) {
    if (jq == ph) {
      if (ph == 0) {
#pragma unroll
        for (int g = 0; g < 4; ++g)
#pragma unroll
          for (int nt = 0; nt < 8; ++nt)
#pragma unroll
            for (int r = 0; r < 4; ++r)
              cmb[(g * 16 + lg * 4 + r) * 132 + nt * 16 + lr] = acc[g][nt][r];
      } else {
#pragma unroll
        for (int g = 0; g < 4; ++g)
#pragma unroll
          for (int nt = 0; nt < 8; ++nt)
#pragma unroll
            for (int r = 0; r < 4; ++r)
              cmb[(g * 16 + lg * 4 + r) * 132 + nt * 16 + lr] += acc[g][nt][r];
      }
    }
    __syncthreads();
  }
  // epilogue: /den + elu + coalesced f16 store. thread t: row t>>2, 32-col seg t&3
  {
    int row = t >> 2, seg = t & 3;
    const float* rgp = cmb + row * 132 + seg * 32;
    float dsum = denL[0][row] + denL[1][row] + denL[2][row] + denL[3][row];
    float rc = __builtin_amdgcn_rcpf(dsum);
    _Float16* outp = hcat + (size_t)(rowbase + row) * 1024 + h * 128 + seg * 32;
#pragma unroll
    for (int q8 = 0; q8 < 4; ++q8) {
      f32x4 va = *(const f32x4*)(rgp + q8 * 8);
      f32x4 vb = *(const f32x4*)(rgp + q8 * 8 + 4);
      float x[8];
#pragma unroll
      for (int c = 0; c < 4; ++c) { x[c] = va[c] * rc; x[4 + c] = vb[c] * rc; }
#pragma unroll
      for (int c = 0; c < 8; ++c) x[c] = x[c] > 0.f ? x[c] : EXP2(x[c] * LOG2E) - 1.f;
      F16x8 o;
      o.h[0] = pkrtz(x[0], x[1]); o.h[1] = pkrtz(x[2], x[3]);
      o.h[2] = pkrtz(x[4], x[5]); o.h[3] = pkrtz(x[6], x[7]);
      *(f16x8*)(outp + q8 * 8) = o.v;
    }
  }
}

// ---------------- k_out: x = elu(cat@W1 + b1); out = LN(nodes + x)
// 256 blocks x 256 thr: 16 rows/block, 4 waves k-split (256 k each), LDS combine.
__global__ __launch_bounds__(256) void k_out(const _Float16* __restrict__ hcat,
    const _Float16* __restrict__ W1t, const float* __restrict__ b1,
    const float* __restrict__ nodes, const float* __restrict__ gamma,
    const float* __restrict__ beta, float* __restrict__ out) {
  __shared__ __align__(16) float part[4][16][132];
  int t = threadIdx.x, w = t >> 6, l = t & 63, lr = l & 15, lg = l >> 4;
  int ibase = blockIdx.x * 16;
  f32x4 acc[8] = {};
  const _Float16* arow = hcat + (size_t)(ibase + lr) * 1024 + w * 256;
  const _Float16* bb = W1t + w * 256;
#pragma unroll
  for (int ks = 0; ks < 8; ++ks) {
    int k0 = ks * 32 + lg * 8;
    f16x8 A = *(const f16x8*)(arow + k0);
#pragma unroll
    for (int nt = 0; nt < 8; ++nt) {
      f16x8 B = *(const f16x8*)(bb + (nt * 16 + lr) * 1024 + k0);
      acc[nt] = __builtin_amdgcn_mfma_f32_16x16x32_f16(A, B, acc[nt], 0, 0, 0);
    }
  }
#pragma unroll
  for (int nt = 0; nt < 8; ++nt)
#pragma unroll
    for (int r = 0; r < 4; ++r)
      part[w][lg * 4 + r][nt * 16 + lr] = acc[nt][r];
  __syncthreads();
  int row = t >> 4, c16 = t & 15;
  int d0 = c16 * 8;
  size_t gi = (size_t)(ibase + row) * 128;
  f32x4 pa = {}, pb = {};
#pragma unroll
  for (int qq = 0; qq < 4; ++qq) {
    pa += *(const f32x4*)&part[qq][row][d0];
    pb += *(const f32x4*)&part[qq][row][d0 + 4];
  }
  f32x4 ba = *(const f32x4*)(b1 + d0), bbv = *(const f32x4*)(b1 + d0 + 4);
  f32x4 na = *(const f32x4*)(nodes + gi + d0), nb = *(const f32x4*)(nodes + gi + d0 + 4);
  float y[8];
  float sum = 0.f, sq = 0.f;
#pragma unroll
  for (int c = 0; c < 4; ++c) {
    float x = pa[c] + ba[c];
    x = x > 0.f ? x : EXP2(x * LOG2E) - 1.f;
    y[c] = x + na[c];
    float x2 = pb[c] + bbv[c];
    x2 = x2 > 0.f ? x2 : EXP2(x2 * LOG2E) - 1.f;
    y[4 + c] = x2 + nb[c];
  }
#pragma unroll
  for (int c = 0; c < 8; ++c) { sum += y[c]; sq += y[c] * y[c]; }
#pragma unroll
  for (int off = 1; off < 16; off <<= 1) {
    sum += __shfl_xor(sum, off, 16);
    sq += __shfl_xor(sq, off, 16);
  }
  float mu = sum * (1.f / 128.f);
  float var = sq * (1.f / 128.f) - mu * mu;
  float rs = __builtin_amdgcn_rsqf(var + EPSLN);
  f32x4 ga = *(const f32x4*)(gamma + d0), gb = *(const f32x4*)(gamma + d0 + 4);
  f32x4 bea = *(const f32x4*)(beta + d0), beb = *(const f32x4*)(beta + d0 + 4);
  f32x4 o0, o1;
#pragma unroll
  for (int c = 0; c < 4; ++c) {
    o0[c] = (y[c] - mu) * rs * ga[c] + bea[c];
    o1[c] = (y[4 + c] - mu) * rs * gb[c] + beb[c];
  }
  *(f32x4*)(out + gi + d0) = o0;
  *(f32x4*)(out + gi + d0 + 4) = o1;
}

extern "C" void kernel_launch(void* const* d_in, const int* in_sizes, int n_in,
                              void* d_out, int out_size, void* d_ws, size_t ws_size,
                              hipStream_t stream) {
  const float* nodes = (const float*)d_in[0];
  const int* adj = (const int*)d_in[1];
  const float* W = (const float*)d_in[2];
  const float* a1 = (const float*)d_in[3];
  const float* a2 = (const float*)d_in[4];
  const float* W1 = (const float*)d_in[5];
  const float* b1 = (const float*)d_in[6];
  const float* gamma = (const float*)d_in[7];
  const float* beta = (const float*)d_in[8];
  float* out = (float*)d_out;
  char* ws = (char*)d_ws;

  const size_t OFF_MASK = 0;                       // 2 MB
  const size_t OFF_WHBT = 2097152;                 // 8.4 MB
  const size_t OFF_F1 = OFF_WHBT + 8388608;        // 128 KB
  const size_t OFF_F2 = OFF_F1 + 131072;           // 128 KB
  const size_t OFF_M2 = OFF_F2 + 131072;           // 256 B
  const size_t OFF_E2T = OFF_M2 + 256;             // 128 KB (f16 tables)
  const size_t OFF_WT = OFF_E2T + 131072;          // 256 KB
  const size_t OFF_W1T = OFF_WT + 262144;          // 256 KB
  const size_t OFF_HCAT = OFF_W1T + 262144;        // 8.4 MB

  unsigned long long* maskT = (unsigned long long*)(ws + OFF_MASK);
  _Float16* Whbt = (_Float16*)(ws + OFF_WHBT);
  float* f1L = (float*)(ws + OFF_F1);
  float* f2L = (float*)(ws + OFF_F2);
  float* M2L = (float*)(ws + OFF_M2);
  _Float16* e2ph = (_Float16*)(ws + OFF_E2T);
  _Float16* Wt = (_Float16*)(ws + OFF_WT);
  _Float16* W1t = (_Float16*)(ws + OFF_W1T);
  _Float16* hcat = (_Float16*)(ws + OFF_HCAT);

  k_packprep<<<17408, 256, 0, stream>>>(adj, maskT, W, W1, Wt, W1t);
  k_wh<<<dim3(64, 8), 256, 0, stream>>>(nodes, Wt, a1, a2, Whbt, f1L, f2L);
  k_m2<<<8, 1024, 0, stream>>>(f2L, M2L, e2ph);
  k_attn<<<512, 256, 0, stream>>>(Whbt, f1L, M2L, e2ph, maskT, hcat);
  k_out<<<256, 256, 0, stream>>>(hcat, W1t, b1, nodes, gamma, beta, out);
}